// Round 11
// baseline (5042.514 us; speedup 1.0000x reference)
//
#include <hip/hip_runtime.h>
#include <hip/hip_bf16.h>

// Sizes (fixed by the reference)
#define BN  256
#define SN  512
#define INN 64
#define HN  256
#define MN  64

// LDS strides (f16 elems unless noted)
#define ZINS 328   // zin: [x(64) | h(256)] + 8 pad
#define ZBS  264   // z0/z1: 256 + 8
#define CFS  72    // cfc: 64 + 8
#define HTS  36    // htmp row stride (f32)

// Output offsets (f32 elements)
#define OFF_ACT  393216
#define OFF_CONF 524288
#define OFF_HN   655360

#define FLAG_STRIDE 32        // u32 per flag slot (128 B line spacing)
#define FLAG_BYTES  16384

typedef _Float16 h8 __attribute__((ext_vector_type(8)));
typedef float fx4 __attribute__((ext_vector_type(4)));
typedef unsigned long long u64;
union h4u { _Float16 h[4]; u64 u; };

__device__ __forceinline__ fx4 mfma16(h8 a, h8 b, fx4 c) {
    return __builtin_amdgcn_mfma_f32_16x16x32_f16(a, b, c, 0, 0, 0);
}
__device__ __forceinline__ float fast_tanh(float x) {
    float e = __expf(2.0f * x);
    return 1.0f - 2.0f / (e + 1.0f);
}
__device__ __forceinline__ float fast_sig(float x) { return 1.0f / (1.0f + __expf(-x)); }
__device__ __forceinline__ float lecun_tanh(float x) { return 1.7159f * fast_tanh(0.666f * x); }
__device__ __forceinline__ float softplus_f(float x) {
    return fmaxf(x, 0.0f) + __logf(1.0f + __expf(-fabsf(x)));
}

template <int NW>
__device__ __forceinline__ h8 loadB(const float* __restrict__ w, int col, int kbase) {
    h8 r;
#pragma unroll
    for (int j = 0; j < 8; ++j) r[j] = (_Float16)w[(kbase + j) * NW + col];
    return r;
}

// lgkm-only barrier: does NOT drain vmcnt (publish stores stay in flight)
#define BAR() do {                                              \
    asm volatile("s_waitcnt lgkmcnt(0)" ::: "memory");          \
    __builtin_amdgcn_s_barrier();                               \
    __builtin_amdgcn_sched_barrier(0);                          \
} while (0)

__global__ void __launch_bounds__(512, 1) lh_scan_kernel(
    const float* __restrict__ x, const float* __restrict__ tsp, const float* __restrict__ hx,
    const float* __restrict__ w0, const float* __restrict__ b0,
    const float* __restrict__ w1, const float* __restrict__ b1,
    const float* __restrict__ f1w, const float* __restrict__ f1b,
    const float* __restrict__ f2w, const float* __restrict__ f2b,
    const float* __restrict__ taw, const float* __restrict__ tab,
    const float* __restrict__ tbw, const float* __restrict__ tbb,
    const float* __restrict__ pw, const float* __restrict__ pbias,
    const float* __restrict__ ihw0, const float* __restrict__ ihb0,
    const float* __restrict__ ihw1, const float* __restrict__ ihb1,
    const float* __restrict__ ahw0, const float* __restrict__ ahb0,
    const float* __restrict__ ahw1, const float* __restrict__ ahb1,
    const float* __restrict__ chw0, const float* __restrict__ chb0,
    const float* __restrict__ chw1, const float* __restrict__ chb1,
    float* __restrict__ out, unsigned int* __restrict__ flags,
    u64* __restrict__ hbuf)
{
    __shared__ __align__(16) _Float16 zinA[16 * ZINS];
    __shared__ __align__(16) _Float16 zinB[16 * ZINS];
    __shared__ __align__(16) _Float16 z0b[16 * ZBS];          // shared A/B (disjoint lifetime)
    __shared__ __align__(16) _Float16 z1b[16 * ZBS];          // shared A/B
    __shared__ __align__(16) _Float16 cfcb[16 * CFS];         // duty (per-block)
    __shared__ __align__(16) _Float16 pfl[8 * 4 * 64 * 8];    // proj B-frags (32 KB)
    __shared__ __align__(16) _Float16 w1l[8 * 8 * 64 * 8];    // W1 cg1 B-frags (64 KB)
    __shared__ __align__(16) float htmp[4 * 16 * HTS];        // shared A/B
    __shared__ float hidI[256];
    __shared__ float hidA[256];
    __shared__ float hidC[128];
    __shared__ float tsbA[2][16], tsbB[2][16];
    __shared__ float wsm[80];

    const int tid  = threadIdx.x;
    const int wv   = tid >> 6;
    const int lane = tid & 63;
    const int lo   = lane & 15;
    const int hi   = lane >> 4;
    const int hi8  = hi * 8;

    const int bid   = blockIdx.x;      // 0..63
    const int xcd   = bid & 7;
    const int c     = bid >> 3;        // column-slice 0..7
    const int gA    = xcd;             // two groups per block, same XCD
    const int gB    = xcd + 8;
    const int bgA   = gA * 16;
    const int bgB   = gB * 16;
    const int sbase = c * 32;

    // ---- small final-layer weights ----
    if (tid < 48)          wsm[tid] = ihw1[tid];
    else if (tid < 51)     wsm[tid] = ihb1[tid - 48];
    else if (tid < 67)     wsm[tid] = ahw1[tid - 51];
    else if (tid == 67)    wsm[67]  = ahb1[0];
    else if (tid < 76)     wsm[tid] = chw1[tid - 68];
    else if (tid == 76)    wsm[76]  = chb1[0];

    // ---- initial state for BOTH groups ----
    {
        int r = tid >> 5, c8 = (tid & 31) * 8;
#pragma unroll
        for (int j = 0; j < 8; ++j) {
            zinA[r * ZINS + 64 + c8 + j] = (_Float16)hx[(bgA + r) * HN + c8 + j];
            zinB[r * ZINS + 64 + c8 + j] = (_Float16)hx[(bgB + r) * HN + c8 + j];
        }
        int c2 = (tid & 31) * 2;
        const float* xa = &x[((size_t)(bgA + r) * SN + 0) * INN + c2];
        const float* xb = &x[((size_t)(bgB + r) * SN + 0) * INN + c2];
        zinA[r * ZINS + c2]     = (_Float16)xa[0];
        zinA[r * ZINS + c2 + 1] = (_Float16)xa[1];
        zinB[r * ZINS + c2]     = (_Float16)xb[0];
        zinB[r * ZINS + c2 + 1] = (_Float16)xb[1];
    }
    if (tid < 16) {
        tsbA[0][tid] = tsp[(bgA + tid) * SN + 0];
        tsbB[0][tid] = tsp[(bgB + tid) * SN + 0];
    }

    // ---- per-lane column biases ----
    const int cg0 = wv, cg1 = wv + 8;
    const float b00 = b0[cg0 * 16 + lo], b01 = b0[cg1 * 16 + lo];
    const float b10 = b1[cg0 * 16 + lo], b11 = b1[cg1 * 16 + lo];

    const int hm   = wv >> 1;
    const int hcol = sbase + (wv & 1) * 16 + lo;
    const float* hwp = (hm == 0) ? f1w : (hm == 1) ? f2w : (hm == 2) ? taw : tbw;
    const float* hbp = (hm == 0) ? f1b : (hm == 1) ? f2b : (hm == 2) ? tab : tbb;
    const float hb = hbp[hcol];

    // ---- register-resident weight fragments (same layout as R5: 128-reg fit) ----
    h8 w0f0[10], w0f1[10], w1f0[8], hdf[8];
#pragma unroll
    for (int kk = 0; kk < 10; ++kk) {
        w0f0[kk] = loadB<256>(w0, cg0 * 16 + lo, kk * 32 + hi8);
        w0f1[kk] = loadB<256>(w0, cg1 * 16 + lo, kk * 32 + hi8);
    }
#pragma unroll
    for (int kk = 0; kk < 8; ++kk) {
        w1f0[kk] = loadB<256>(w1, cg0 * 16 + lo, kk * 32 + hi8);
        hdf[kk]  = loadB<256>(hwp, hcol, kk * 32 + hi8);
        h8 f = loadB<256>(w1, cg1 * 16 + lo, kk * 32 + hi8);
        *(h8*)&w1l[((kk * 8 + wv) * 64 + lane) * 8] = f;
    }
    if (wv < 4) {
#pragma unroll
        for (int kk = 0; kk < 8; ++kk) {
            h8 f = loadB<64>(pw, wv * 16 + lo, kk * 32 + hi8);
            *(h8*)&pfl[((kk * 4 + wv) * 64 + lane) * 8] = f;
        }
    }
    float pbv = 0.0f;
    if (wv >= 2 && wv < 6) pbv = pbias[(wv - 2) * 16 + lo];
    h8 hwf[2] = {};
    float hbv = 0.0f;
    if (wv == 2) {
        hbv = ihb0[lo];
#pragma unroll
        for (int kk = 0; kk < 2; ++kk) hwf[kk] = loadB<16>(ihw0, lo, kk * 32 + hi8);
    } else if (wv == 3) {
        hbv = ahb0[lo];
#pragma unroll
        for (int kk = 0; kk < 2; ++kk) hwf[kk] = loadB<16>(ahw0, lo, kk * 32 + hi8);
    } else if (wv == 4) {
        int cc = (lo < 8) ? lo : 0;
        hbv = (lo < 8) ? chb0[lo] : 0.0f;
#pragma unroll
        for (int kk = 0; kk < 2; ++kk) hwf[kk] = loadB<8>(chw0, cc, kk * 32 + hi8);
    }

    __syncthreads();

// One sub-step for group (ZIN,TSB,G,BG). PR: duty block id. PCOND/PG/PVAL: deferred
// flag post for the OTHER group's previous publish. LCOND/LG/LVAL/LZIN: poll+load
// of the other group's h(LVAL) into LZIN.
#define SUB(ZIN, TSB, G, BG, PR, PCOND, PG, PVAL, LCOND, LG, LVAL, LZIN)                      \
  {                                                                                           \
    const bool cv = (t < SN);                                                                 \
    const bool dt = (t >= 1) && (c == (PR));                                                  \
    if ((PCOND) && tid == 0) {                                                                \
        asm volatile("s_waitcnt vmcnt(0)" ::: "memory");                                      \
        __hip_atomic_store(&flags[((PG) * 8 + c) * FLAG_STRIDE], (unsigned)(PVAL),            \
                           __ATOMIC_RELAXED, __HIP_MEMORY_SCOPE_AGENT);                       \
    }                                                                                         \
    /* P1: z0 = lecun([x|h] @ W0 + b0) */                                                     \
    if (cv) {                                                                                 \
        fx4 a0 = {b00, b00, b00, b00}, a1 = {b01, b01, b01, b01};                             \
        _Pragma("unroll")                                                                     \
        for (int kk = 0; kk < 10; ++kk) {                                                     \
            h8 a = *(const h8*)&ZIN[lo * ZINS + kk * 32 + hi8];                               \
            a0 = mfma16(a, w0f0[kk], a0);                                                     \
            a1 = mfma16(a, w0f1[kk], a1);                                                     \
        }                                                                                     \
        _Pragma("unroll")                                                                     \
        for (int i = 0; i < 4; ++i) {                                                         \
            int r = hi * 4 + i;                                                               \
            z0b[r * ZBS + cg0 * 16 + lo] = (_Float16)lecun_tanh(a0[i]);                       \
            z0b[r * ZBS + cg1 * 16 + lo] = (_Float16)lecun_tanh(a1[i]);                       \
        }                                                                                     \
    }                                                                                         \
    BAR();                                                                                    \
    /* P2: x/ts prefetch(t+1) + z1 */                                                         \
    if (t + 1 < SN) {                                                                         \
        int r = tid >> 5, c2 = (tid & 31) * 2;                                                \
        const float* xp = &x[((size_t)((BG) + r) * SN + (t + 1)) * INN + c2];                 \
        ZIN[r * ZINS + c2]     = (_Float16)xp[0];                                             \
        ZIN[r * ZINS + c2 + 1] = (_Float16)xp[1];                                             \
        if (tid < 16) TSB[(t + 1) & 1][tid] = tsp[((BG) + tid) * SN + t + 1];                 \
    }                                                                                         \
    if (cv) {                                                                                 \
        fx4 a0 = {b10, b10, b10, b10}, a1 = {b11, b11, b11, b11};                             \
        _Pragma("unroll")                                                                     \
        for (int kk = 0; kk < 8; ++kk) {                                                      \
            h8 a  = *(const h8*)&z0b[lo * ZBS + kk * 32 + hi8];                               \
            h8 bf = *(const h8*)&w1l[((kk * 8 + wv) * 64 + lane) * 8];                        \
            a0 = mfma16(a, w1f0[kk], a0);                                                     \
            a1 = mfma16(a, bf, a1);                                                           \
        }                                                                                     \
        _Pragma("unroll")                                                                     \
        for (int i = 0; i < 4; ++i) {                                                         \
            int r = hi * 4 + i;                                                               \
            z1b[r * ZBS + cg0 * 16 + lo] = (_Float16)lecun_tanh(a0[i]);                       \
            z1b[r * ZBS + cg1 * 16 + lo] = (_Float16)lecun_tanh(a1[i]);                       \
        }                                                                                     \
    }                                                                                         \
    BAR();                                                                                    \
    /* P3: heads */                                                                           \
    if (cv) {                                                                                 \
        fx4 acc = {hb, hb, hb, hb};                                                           \
        _Pragma("unroll")                                                                     \
        for (int kk = 0; kk < 8; ++kk) {                                                      \
            h8 a = *(const h8*)&z1b[lo * ZBS + kk * 32 + hi8];                                \
            acc = mfma16(a, hdf[kk], acc);                                                    \
        }                                                                                     \
        _Pragma("unroll")                                                                     \
        for (int i = 0; i < 4; ++i)                                                           \
            htmp[(hm * 16 + hi * 4 + i) * HTS + (wv & 1) * 16 + lo] = acc[i];                 \
    }                                                                                         \
    BAR();                                                                                    \
    /* P4: combine+publish (wave 0 only) || duty proj (waves 2-5) */                          \
    if (cv && wv == 0) {                                                                      \
        int r = lane >> 2, cb = (lane & 3) * 8;                                               \
        float tv = TSB[t & 1][r];                                                             \
        h4u pk0, pk1;                                                                         \
        _Pragma("unroll")                                                                     \
        for (int k = 0; k < 8; ++k) {                                                         \
            int cc = cb + k;                                                                  \
            float ff1 = fast_tanh(htmp[(0 * 16 + r) * HTS + cc]);                             \
            float ff2 = fast_tanh(htmp[(1 * 16 + r) * HTS + cc]);                             \
            float ti  = fast_sig(htmp[(2 * 16 + r) * HTS + cc] * tv                           \
                                 + htmp[(3 * 16 + r) * HTS + cc]);                            \
            float hn  = ff1 + ti * (ff2 - ff1);                                               \
            if (k < 4) pk0.h[k] = (_Float16)hn; else pk1.h[k - 4] = (_Float16)hn;             \
            if (t == SN - 1) out[OFF_HN + ((BG) + r) * HN + sbase + cc] = hn;                 \
        }                                                                                     \
        size_t idx = (((size_t)((t + 1) & 1) * 256) + (G) * 16 + r) * 64 + (sbase + cb) / 4;  \
        __hip_atomic_store(&hbuf[idx],     pk0.u, __ATOMIC_RELAXED, __HIP_MEMORY_SCOPE_AGENT);\
        __hip_atomic_store(&hbuf[idx + 1], pk1.u, __ATOMIC_RELAXED, __HIP_MEMORY_SCOPE_AGENT);\
    }                                                                                         \
    if (dt && wv >= 2 && wv < 6) {                                                            \
        int u = wv - 2;                                                                       \
        fx4 acc = {pbv, pbv, pbv, pbv};                                                       \
        _Pragma("unroll")                                                                     \
        for (int kk = 0; kk < 8; ++kk) {                                                      \
            h8 a = *(const h8*)&ZIN[lo * ZINS + 64 + kk * 32 + hi8];                          \
            h8 b = *(const h8*)&pfl[((kk * 4 + u) * 64 + lane) * 8];                          \
            acc = mfma16(a, b, acc);                                                          \
        }                                                                                     \
        _Pragma("unroll")                                                                     \
        for (int i = 0; i < 4; ++i)                                                           \
            cfcb[(hi * 4 + i) * CFS + u * 16 + lo] = (_Float16)acc[i];                        \
    }                                                                                         \
    BAR();                                                                                    \
    /* P5: duty hiddens (waves 2-4) || poll (wave 7) */                                       \
    if (dt && wv >= 2 && wv < 5) {                                                            \
        fx4 acc = {hbv, hbv, hbv, hbv};                                                       \
        _Pragma("unroll")                                                                     \
        for (int kk = 0; kk < 2; ++kk) {                                                      \
            h8 a = *(const h8*)&cfcb[lo * CFS + kk * 32 + hi8];                               \
            acc = mfma16(a, hwf[kk], acc);                                                    \
        }                                                                                     \
        _Pragma("unroll")                                                                     \
        for (int i = 0; i < 4; ++i) {                                                         \
            float v = acc[i];                                                                 \
            v = v * fast_sig(v);                                                              \
            int r = hi * 4 + i;                                                               \
            if (wv == 2)       hidI[r * 16 + lo] = v;                                         \
            else if (wv == 3)  hidA[r * 16 + lo] = v;                                         \
            else if (lo < 8)   hidC[r * 8 + lo]  = v;                                         \
        }                                                                                     \
    }                                                                                         \
    if ((LCOND) && wv == 7 && lane < 8) {                                                     \
        while (__hip_atomic_load(&flags[((LG) * 8 + lane) * FLAG_STRIDE],                     \
                __ATOMIC_RELAXED, __HIP_MEMORY_SCOPE_AGENT) < (unsigned)(LVAL)) {}            \
    }                                                                                         \
    BAR();                                                                                    \
    /* P6: h-load into LZIN + duty outputs(t-1) */                                            \
    {                                                                                         \
        u64 hv0 = 0, hv1 = 0;                                                                 \
        int lr = tid >> 5, lc8 = (tid & 31) * 8;                                              \
        if (LCOND) {                                                                          \
            size_t idx = (((size_t)((LVAL) & 1) * 256) + (LG) * 16 + lr) * 64 + lc8 / 4;      \
            hv0 = __hip_atomic_load(&hbuf[idx],     __ATOMIC_RELAXED, __HIP_MEMORY_SCOPE_AGENT);\
            hv1 = __hip_atomic_load(&hbuf[idx + 1], __ATOMIC_RELAXED, __HIP_MEMORY_SCOPE_AGENT);\
        }                                                                                     \
        if (dt && tid >= 384 && tid < 464) {                                                  \
            int local = tid - 384;                                                            \
            int rr = local / 5, o = local % 5;                                                \
            int tc = t - 1;                                                                   \
            int b = (BG) + rr;                                                                \
            if (o < 3) {                                                                      \
                float s = wsm[48 + o];                                                        \
                _Pragma("unroll")                                                             \
                for (int u = 0; u < 16; ++u) s += hidI[rr * 16 + u] * wsm[u * 3 + o];         \
                out[(size_t)(b * SN + tc) * 3 + o] = softplus_f(s);                           \
            } else if (o == 3) {                                                              \
                float s = wsm[67];                                                            \
                _Pragma("unroll")                                                             \
                for (int u = 0; u < 16; ++u) s += hidA[rr * 16 + u] * wsm[51 + u];            \
                out[OFF_ACT + b * SN + tc] = fast_tanh(s);                                    \
            } else {                                                                          \
                float s = wsm[76];                                                            \
                _Pragma("unroll")                                                             \
                for (int u = 0; u < 8; ++u) s += hidC[rr * 8 + u] * wsm[68 + u];              \
                out[OFF_CONF + b * SN + tc] = fast_sig(s);                                    \
            }                                                                                 \
        }                                                                                     \
        if (LCOND) {                                                                          \
            *(u64*)&LZIN[lr * ZINS + 64 + lc8]     = hv0;                                     \
            *(u64*)&LZIN[lr * ZINS + 64 + lc8 + 4] = hv1;                                     \
        }                                                                                     \
    }                                                                                         \
    BAR();                                                                                    \
  }

    for (int t = 0; t <= SN; ++t) {
        // substep A: compute group gA step t; exchange for gB's h(t) completes underneath
        SUB(zinA, tsbA, gA, bgA, (t & 7),
            /*post flag_B = t   */ (t >= 1), gB, t,
            /*poll+load h_B(t)  */ (t >= 1), gB, t, zinB);
        // substep B: compute group gB step t; exchange for gA's h(t+1) completes underneath
        SUB(zinB, tsbB, gB, bgB, ((t + 4) & 7),
            /*post flag_A = t+1 */ (t < SN), gA, t + 1,
            /*poll+load h_A(t+1)*/ (t < SN), gA, t + 1, zinA);
    }
#undef SUB
}

extern "C" void kernel_launch(void* const* d_in, const int* in_sizes, int n_in,
                              void* d_out, int out_size, void* d_ws, size_t ws_size,
                              hipStream_t stream) {
    (void)in_sizes; (void)n_in; (void)out_size; (void)ws_size;
    const float* p[29];
    for (int i = 0; i < 29; ++i) p[i] = (const float*)d_in[i];
    unsigned int* flags = (unsigned int*)d_ws;
    u64* hbuf = (u64*)((char*)d_ws + FLAG_BYTES);
    hipMemsetAsync(d_ws, 0, FLAG_BYTES, stream);
    hipLaunchKernelGGL(lh_scan_kernel, dim3(64), dim3(512), 0, stream,
        p[0], p[1], p[2], p[3], p[4], p[5], p[6], p[7], p[8], p[9], p[10], p[11], p[12],
        p[13], p[14], p[15], p[16], p[17], p[18], p[19], p[20], p[21], p[22], p[23],
        p[24], p[25], p[26], p[27], p[28], (float*)d_out, flags, hbuf);
}

// Round 12
// 2390.496 us; speedup vs baseline: 2.1094x; 2.1094x over previous
//
#include <hip/hip_runtime.h>
#include <hip/hip_bf16.h>

// Sizes (fixed by the reference)
#define BN  256
#define SN  512
#define INN 64
#define HN  256
#define MN  64

// LDS strides (f16 elems unless noted)
#define ZINS 328   // zin: [x(64) | h(256)] + 8 pad
#define ZBS  264   // z0/z1: 256 + 8
#define CFS  72    // cfc: 64 + 8
#define HTS  36    // htmp row stride (f32)

// Output offsets (f32 elements)
#define OFF_ACT  393216
#define OFF_CONF 524288
#define OFF_HN   655360

#define HBUF_OFF 16384        // byte offset of hbuf in d_ws (kept from R5 layout)
#define HBUF_BYTES (2 * 256 * 64 * 8)   // 2 slots * 256 rows * 64 u64 = 256 KB

typedef _Float16 h8 __attribute__((ext_vector_type(8)));
typedef float fx4 __attribute__((ext_vector_type(4)));
typedef unsigned long long u64;
union h4u { _Float16 h[4]; unsigned short s[4]; u64 u; };

__device__ __forceinline__ fx4 mfma16(h8 a, h8 b, fx4 c) {
    return __builtin_amdgcn_mfma_f32_16x16x32_f16(a, b, c, 0, 0, 0);
}
__device__ __forceinline__ float fast_tanh(float x) {
    float e = __expf(2.0f * x);
    return 1.0f - 2.0f / (e + 1.0f);
}
__device__ __forceinline__ float fast_sig(float x) { return 1.0f / (1.0f + __expf(-x)); }
__device__ __forceinline__ float lecun_tanh(float x) { return 1.7159f * fast_tanh(0.666f * x); }
__device__ __forceinline__ float softplus_f(float x) {
    return fmaxf(x, 0.0f) + __logf(1.0f + __expf(-fabsf(x)));
}

template <int NW>
__device__ __forceinline__ h8 loadB(const float* __restrict__ w, int col, int kbase) {
    h8 r;
#pragma unroll
    for (int j = 0; j < 8; ++j) r[j] = (_Float16)w[(kbase + j) * NW + col];
    return r;
}

__global__ void __launch_bounds__(512, 1) lh_scan_kernel(
    const float* __restrict__ x, const float* __restrict__ tsp, const float* __restrict__ hx,
    const float* __restrict__ w0, const float* __restrict__ b0,
    const float* __restrict__ w1, const float* __restrict__ b1,
    const float* __restrict__ f1w, const float* __restrict__ f1b,
    const float* __restrict__ f2w, const float* __restrict__ f2b,
    const float* __restrict__ taw, const float* __restrict__ tab,
    const float* __restrict__ tbw, const float* __restrict__ tbb,
    const float* __restrict__ pw, const float* __restrict__ pbias,
    const float* __restrict__ ihw0, const float* __restrict__ ihb0,
    const float* __restrict__ ihw1, const float* __restrict__ ihb1,
    const float* __restrict__ ahw0, const float* __restrict__ ahb0,
    const float* __restrict__ ahw1, const float* __restrict__ ahb1,
    const float* __restrict__ chw0, const float* __restrict__ chb0,
    const float* __restrict__ chw1, const float* __restrict__ chb1,
    float* __restrict__ out, u64* __restrict__ hbuf)
{
    __shared__ __align__(16) _Float16 zin[16 * ZINS];
    __shared__ __align__(16) _Float16 z0b[16 * ZBS];
    __shared__ __align__(16) _Float16 z1b[16 * ZBS];
    __shared__ __align__(16) _Float16 cfcb[16 * CFS];
    __shared__ __align__(16) _Float16 pfl[8 * 4 * 64 * 8];   // proj B-frags
    __shared__ __align__(16) _Float16 w1l[8 * 8 * 64 * 8];   // W1 cg1 B-frags
    __shared__ __align__(16) float htmp[4 * 16 * HTS];
    __shared__ float hidI[16 * 16];
    __shared__ float hidA[16 * 16];
    __shared__ float hidC[16 * 8];
    __shared__ float tsb[2][16];
    __shared__ float wsm[80];

    const int tid  = threadIdx.x;
    const int wv   = tid >> 6;
    const int lane = tid & 63;
    const int lo   = lane & 15;
    const int hi   = lane >> 4;
    const int hi8  = hi * 8;

    const int bid   = blockIdx.x;
    const int xcd   = bid & 7;
    const int c     = (bid >> 3) & 7;   // column-slice id 0..7
    const int gsel  = bid >> 6;
    const int g     = xcd + 8 * gsel;   // batch group; 8 blocks share g
    const int bg    = g * 16;
    const int sbase = c * 32;           // this block's 32 head columns

    // ---- small final-layer weights to LDS ----
    if (tid < 48)          wsm[tid] = ihw1[tid];
    else if (tid < 51)     wsm[tid] = ihb1[tid - 48];
    else if (tid < 67)     wsm[tid] = ahw1[tid - 51];
    else if (tid == 67)    wsm[67]  = ahb1[0];
    else if (tid < 76)     wsm[tid] = chw1[tid - 68];
    else if (tid == 76)    wsm[76]  = chb1[0];

    // ---- initial state ----
    {
        int r = tid >> 5, c8 = (tid & 31) * 8;
#pragma unroll
        for (int j = 0; j < 8; ++j)
            zin[r * ZINS + 64 + c8 + j] = (_Float16)hx[(bg + r) * HN + c8 + j];
        int c2 = (tid & 31) * 2;
        const float* xp = &x[((size_t)(bg + r) * SN + 0) * INN + c2];
        zin[r * ZINS + c2]     = (_Float16)xp[0];
        zin[r * ZINS + c2 + 1] = (_Float16)xp[1];
    }
    if (tid < 16) tsb[0][tid] = tsp[(bg + tid) * SN + 0];

    // ---- per-lane column biases ----
    const int cg0 = wv, cg1 = wv + 8;
    const float b00 = b0[cg0 * 16 + lo], b01 = b0[cg1 * 16 + lo];
    const float b10 = b1[cg0 * 16 + lo], b11 = b1[cg1 * 16 + lo];

    const int hm   = wv >> 1;
    const int hcol = sbase + (wv & 1) * 16 + lo;
    const float* hwp = (hm == 0) ? f1w : (hm == 1) ? f2w : (hm == 2) ? taw : tbw;
    const float* hbp = (hm == 0) ? f1b : (hm == 1) ? f2b : (hm == 2) ? tab : tbb;
    const float hb = hbp[hcol];

    // ---- register-resident weight fragments ----
    h8 w0f0[10], w0f1[10], w1f0[8], hdf[8];
#pragma unroll
    for (int kk = 0; kk < 10; ++kk) {
        w0f0[kk] = loadB<256>(w0, cg0 * 16 + lo, kk * 32 + hi8);
        w0f1[kk] = loadB<256>(w0, cg1 * 16 + lo, kk * 32 + hi8);
    }
#pragma unroll
    for (int kk = 0; kk < 8; ++kk) {
        w1f0[kk] = loadB<256>(w1, cg0 * 16 + lo, kk * 32 + hi8);
        hdf[kk]  = loadB<256>(hwp, hcol, kk * 32 + hi8);
        h8 f = loadB<256>(w1, cg1 * 16 + lo, kk * 32 + hi8);
        *(h8*)&w1l[((kk * 8 + wv) * 64 + lane) * 8] = f;
    }
    // proj fragments -> LDS (all blocks: proj duty rotates)
    float pbv = 0.0f;
    if (wv < 4) {
        pbv = pbias[wv * 16 + lo];
#pragma unroll
        for (int kk = 0; kk < 8; ++kk) {
            h8 f = loadB<64>(pw, wv * 16 + lo, kk * 32 + hi8);
            *(h8*)&pfl[((kk * 4 + wv) * 64 + lane) * 8] = f;
        }
    }
    h8 hwf[2] = {};
    float hbv = 0.0f;
    if (wv == 4) {
        hbv = ihb0[lo];
#pragma unroll
        for (int kk = 0; kk < 2; ++kk) hwf[kk] = loadB<16>(ihw0, lo, kk * 32 + hi8);
    } else if (wv == 5) {
        hbv = ahb0[lo];
#pragma unroll
        for (int kk = 0; kk < 2; ++kk) hwf[kk] = loadB<16>(ahw0, lo, kk * 32 + hi8);
    } else if (wv == 6) {
        int cc = (lo < 8) ? lo : 0;
        hbv = (lo < 8) ? chb0[lo] : 0.0f;
#pragma unroll
        for (int kk = 0; kk < 2; ++kk) hwf[kk] = loadB<8>(chw0, cc, kk * 32 + hi8);
    }

    __syncthreads();

    for (int t = 0; t <= SN; ++t) {
        const int pr = t & 7;   // which block does proj/outputs this step
        // epoch tag for h(t+1): 2 bits, never equals the slot's previous content
        const unsigned tagc = ((((unsigned)(t + 1)) >> 1) + 1u) & 3u;

        // ===== z0 = lecun([x|h] @ W0 + b0) =====
        if (t < SN) {
            fx4 a0 = {b00, b00, b00, b00}, a1 = {b01, b01, b01, b01};
#pragma unroll
            for (int kk = 0; kk < 10; ++kk) {
                h8 a = *(const h8*)&zin[lo * ZINS + kk * 32 + hi8];
                a0 = mfma16(a, w0f0[kk], a0);
                a1 = mfma16(a, w0f1[kk], a1);
            }
#pragma unroll
            for (int i = 0; i < 4; ++i) {
                int r = hi * 4 + i;
                z0b[r * ZBS + cg0 * 16 + lo] = (_Float16)lecun_tanh(a0[i]);
                z0b[r * ZBS + cg1 * 16 + lo] = (_Float16)lecun_tanh(a1[i]);
            }
        }
        __syncthreads();  // S1

        // x/ts prefetch for t+1 (x region of zin is dead after z0)
        if (t + 1 < SN) {
            int r = tid >> 5, c2 = (tid & 31) * 2;
            const float* xp = &x[((size_t)(bg + r) * SN + (t + 1)) * INN + c2];
            zin[r * ZINS + c2]     = (_Float16)xp[0];
            zin[r * ZINS + c2 + 1] = (_Float16)xp[1];
            if (tid < 16) tsb[(t + 1) & 1][tid] = tsp[(bg + tid) * SN + t + 1];
        }

        // ===== z1 = lecun(z0 @ W1 + b1) =====
        if (t < SN) {
            fx4 a0 = {b10, b10, b10, b10}, a1 = {b11, b11, b11, b11};
#pragma unroll
            for (int kk = 0; kk < 8; ++kk) {
                h8 a = *(const h8*)&z0b[lo * ZBS + kk * 32 + hi8];
                h8 bf = *(const h8*)&w1l[((kk * 8 + wv) * 64 + lane) * 8];
                a0 = mfma16(a, w1f0[kk], a0);
                a1 = mfma16(a, bf, a1);
            }
#pragma unroll
            for (int i = 0; i < 4; ++i) {
                int r = hi * 4 + i;
                z1b[r * ZBS + cg0 * 16 + lo] = (_Float16)lecun_tanh(a0[i]);
                z1b[r * ZBS + cg1 * 16 + lo] = (_Float16)lecun_tanh(a1[i]);
            }
        }
        __syncthreads();  // S2

        // ===== head unit: (matrix hm, colgroup wv&1) of this block's 32-col slice =====
        if (t < SN) {
            fx4 acc = {hb, hb, hb, hb};
#pragma unroll
            for (int kk = 0; kk < 8; ++kk) {
                h8 a = *(const h8*)&z1b[lo * ZBS + kk * 32 + hi8];
                acc = mfma16(a, hdf[kk], acc);
            }
#pragma unroll
            for (int i = 0; i < 4; ++i)
                htmp[(hm * 16 + hi * 4 + i) * HTS + (wv & 1) * 16 + lo] = acc[i];
        }
        __syncthreads();  // S3

        // ===== combine -> h_new slice (4 cols/thread) -> TAGGED coherent u64 store =====
        if (t < SN && tid < 128) {
            int r = tid >> 3, c4 = (tid & 7) * 4;
            h4u pk;
            float tv = tsb[t & 1][r];
#pragma unroll
            for (int k = 0; k < 4; ++k) {
                float a1v = htmp[(0 * 16 + r) * HTS + c4 + k];
                float a2v = htmp[(1 * 16 + r) * HTS + c4 + k];
                float a3v = htmp[(2 * 16 + r) * HTS + c4 + k];
                float a4v = htmp[(3 * 16 + r) * HTS + c4 + k];
                float ff1 = fast_tanh(a1v);
                float ff2 = fast_tanh(a2v);
                float ti  = fast_sig(a3v * tv + a4v);
                float hn  = ff1 + ti * (ff2 - ff1);
                pk.h[k] = (_Float16)hn;
                // embed epoch tag: f16[even] LSB = tag bit0, f16[odd] LSB = tag bit1
                unsigned tb = (k & 1) ? ((tagc >> 1) & 1u) : (tagc & 1u);
                pk.s[k] = (unsigned short)((pk.s[k] & 0xFFFEu) | tb);
                if (t == SN - 1) out[OFF_HN + (bg + r) * HN + sbase + c4 + k] = hn;
            }
            size_t idx = (((size_t)((t + 1) & 1) * 256) + g * 16 + r) * 64 + (sbase + c4) / 4;
            __hip_atomic_store(&hbuf[idx], pk.u, __ATOMIC_RELAXED, __HIP_MEMORY_SCOPE_AGENT);
        }
        __syncthreads();  // S4

        // ===== overlap: proj(t-1) on the rotating block =====
        if (t >= 1 && c == pr && wv < 4) {
            fx4 acc = {pbv, pbv, pbv, pbv};
#pragma unroll
            for (int kk = 0; kk < 8; ++kk) {
                h8 a = *(const h8*)&zin[lo * ZINS + 64 + kk * 32 + hi8];
                h8 b = *(const h8*)&pfl[((kk * 4 + wv) * 64 + lane) * 8];
                acc = mfma16(a, b, acc);
            }
#pragma unroll
            for (int i = 0; i < 4; ++i)
                cfcb[(hi * 4 + i) * CFS + wv * 16 + lo] = (_Float16)acc[i];
        }
        __syncthreads();  // S5

        if (t >= 1 && c == pr && wv >= 4 && wv < 7) {
            fx4 acc = {hbv, hbv, hbv, hbv};
#pragma unroll
            for (int kk = 0; kk < 2; ++kk) {
                h8 a = *(const h8*)&cfcb[lo * CFS + kk * 32 + hi8];
                acc = mfma16(a, hwf[kk], acc);
            }
#pragma unroll
            for (int i = 0; i < 4; ++i) {
                float v = acc[i];
                v = v * fast_sig(v);
                int r = hi * 4 + i;
                if (wv == 4)       hidI[r * 16 + lo] = v;
                else if (wv == 5)  hidA[r * 16 + lo] = v;
                else if (lo < 8)   hidC[r * 8 + lo]  = v;
            }
        }
        __syncthreads();  // S6

        if (t >= 1 && c == pr && tid < 80) {
            int r = tid / 5, o = tid % 5;
            int tc = t - 1;
            int b = bg + r;
            if (o < 3) {
                float s = wsm[48 + o];
#pragma unroll
                for (int u = 0; u < 16; ++u) s += hidI[r * 16 + u] * wsm[u * 3 + o];
                out[(size_t)(b * SN + tc) * 3 + o] = softplus_f(s);
            } else if (o == 3) {
                float s = wsm[67];
#pragma unroll
                for (int u = 0; u < 16; ++u) s += hidA[r * 16 + u] * wsm[51 + u];
                out[OFF_ACT + b * SN + tc] = fast_tanh(s);
            } else {
                float s = wsm[76];
#pragma unroll
                for (int u = 0; u < 8; ++u) s += hidC[r * 8 + u] * wsm[68 + u];
                out[OFF_CONF + b * SN + tc] = fast_sig(s);
            }
        }

        // ===== tag-spin load of h(t+1): single coherence round-trip, no flags =====
        if (t < SN) {
            int r = tid >> 5, c8 = (tid & 31) * 8;
            size_t idx = (((size_t)((t + 1) & 1) * 256) + g * 16 + r) * 64 + c8 / 4;
            const unsigned b0e = tagc & 1u, b1e = (tagc >> 1) & 1u;
            u64 v0 = __hip_atomic_load(&hbuf[idx],     __ATOMIC_RELAXED, __HIP_MEMORY_SCOPE_AGENT);
            u64 v1 = __hip_atomic_load(&hbuf[idx + 1], __ATOMIC_RELAXED, __HIP_MEMORY_SCOPE_AGENT);
            while ((unsigned)(v0 & 1u) != b0e || (unsigned)((v0 >> 16) & 1u) != b1e)
                v0 = __hip_atomic_load(&hbuf[idx],     __ATOMIC_RELAXED, __HIP_MEMORY_SCOPE_AGENT);
            while ((unsigned)(v1 & 1u) != b0e || (unsigned)((v1 >> 16) & 1u) != b1e)
                v1 = __hip_atomic_load(&hbuf[idx + 1], __ATOMIC_RELAXED, __HIP_MEMORY_SCOPE_AGENT);
            *(u64*)&zin[r * ZINS + 64 + c8]     = v0;
            *(u64*)&zin[r * ZINS + 64 + c8 + 4] = v1;
        }
        __syncthreads();  // S7
    }
}

extern "C" void kernel_launch(void* const* d_in, const int* in_sizes, int n_in,
                              void* d_out, int out_size, void* d_ws, size_t ws_size,
                              hipStream_t stream) {
    (void)in_sizes; (void)n_in; (void)out_size; (void)ws_size;
    const float* p[29];
    for (int i = 0; i < 29; ++i) p[i] = (const float*)d_in[i];
    u64* hbuf = (u64*)((char*)d_ws + HBUF_OFF);
    // poison hbuf with tag pattern 0 (0xAAAA: LSBs 0) — expected tags start at 1,2,3,...
    hipMemsetAsync(hbuf, 0xAA, HBUF_BYTES, stream);
    hipLaunchKernelGGL(lh_scan_kernel, dim3(128), dim3(512), 0, stream,
        p[0], p[1], p[2], p[3], p[4], p[5], p[6], p[7], p[8], p[9], p[10], p[11], p[12],
        p[13], p[14], p[15], p[16], p[17], p[18], p[19], p[20], p[21], p[22], p[23],
        p[24], p[25], p[26], p[27], p[28], (float*)d_out, hbuf);
}